// Round 5
// baseline (756.471 us; speedup 1.0000x reference)
//
#include <hip/hip_runtime.h>

// DualMem fast_get_image_pred, fully fused:
//   logits[b,c] = 100 * (Σ_m w_m sim_m) / sqrt(Σ_{i,j} w_i w_j G[c,i,j])
//
// R4 lesson: sim_kernel was L1-BW bound — mem addresses depended only on
// tid&3, so every wave-wide 16B load moved 1KB through L1 with 64B distinct
// (3.1 GB L1 traffic ~= the 105us). Fix: stage mem[c] in LDS once (LDS
// broadcast is free), keep img direct-from-global (lane-distinct, L2-hot),
// give each sim thread 4 b-rows (acc[4][11]=44 persistent, under the ~70
// spill line learned in R2/R3). Gram runs as a 5th wave off the same staged
// LDS. Epilogue fused in-block. One dispatch, two barriers.

constexpr int Bn = 64;     // batch
constexpr int Cn = 1000;   // classes
constexpr int Mn = 11;     // memories per class
constexpr int Dn = 1024;   // feature dim
constexpr int NP = 66;     // Mn*(Mn+1)/2 unique Gram pairs
constexpr float BETA = 5.5f;

// p-th pair (i<=j) of the upper-triangular 11x11 Gram (compile-time p only!)
constexpr int pairI(int p) {
    int i = 0;
    while (p >= Mn - i) { p -= Mn - i; ++i; }
    return i;
}
constexpr int pairJ(int p) {
    int i = 0;
    while (p >= Mn - i) { p -= Mn - i; ++i; }
    return i + p;
}

template <int P0, int P1>
__device__ inline void gramPairs(const float4* v, float* g) {
#pragma unroll
    for (int p = P0; p < P1; ++p) {           // p compile-time after unroll
        const float4 a = v[pairI(p)];
        const float4 b = v[pairJ(p)];
        float x = g[p - P0];
        x = fmaf(a.x, b.x, x);
        x = fmaf(a.y, b.y, x);
        x = fmaf(a.z, b.z, x);
        x = fmaf(a.w, b.w, x);
        g[p - P0] = x;
    }
}

__global__ __launch_bounds__(320) void dualmem_kernel(
    const float* __restrict__ img, const float* __restrict__ mem,
    float* __restrict__ out) {
    __shared__ float memL[Mn * Dn];   // staged mem[c], linear (45 KB)
    __shared__ float redS[Bn * Mn];   // reduced sims  [b][m]
    __shared__ float redG[NP];        // reduced Gram pairs

    const int c   = blockIdx.x;
    const int tid = threadIdx.x;
    const float* __restrict__ memc = mem + (size_t)c * (Mn * Dn);

    // ---- stage mem[c] into LDS: coalesced float4, all 320 threads
    for (int u = tid; u < Mn * Dn / 4; u += 320) {
        const float4 v = *reinterpret_cast<const float4*>(memc + 4 * u);
        *reinterpret_cast<float4*>(&memL[4 * u]) = v;
    }
    __syncthreads();

    if (tid < 256) {
        // ---- sim waves: thread (bg, ds) owns b = 4bg..4bg+3, d = 4ds+64k+{0..3}
        const int ds = tid & 15;
        const int bg = tid >> 4;

        float acc[4][Mn];
#pragma unroll
        for (int i = 0; i < 4; ++i)
#pragma unroll
            for (int m = 0; m < Mn; ++m) acc[i][m] = 0.f;

        const float* ip = img + (4 * bg) * Dn + 4 * ds;

#pragma unroll 2
        for (int k = 0; k < 16; ++k) {
            float4 iv[4];
#pragma unroll
            for (int i = 0; i < 4; ++i)
                iv[i] = *reinterpret_cast<const float4*>(ip + i * Dn + 64 * k);
#pragma unroll
            for (int m = 0; m < Mn; ++m) {
                const float4 mv = *reinterpret_cast<const float4*>(
                    &memL[m * Dn + 4 * ds + 64 * k]);
#pragma unroll
                for (int i = 0; i < 4; ++i) {
                    float a = acc[i][m];
                    a = fmaf(iv[i].x, mv.x, a);
                    a = fmaf(iv[i].y, mv.y, a);
                    a = fmaf(iv[i].z, mv.z, a);
                    a = fmaf(iv[i].w, mv.w, a);
                    acc[i][m] = a;
                }
            }
        }
        // reduce over the 16 ds lanes (low 4 lane bits)
#pragma unroll
        for (int i = 0; i < 4; ++i)
#pragma unroll
            for (int m = 0; m < Mn; ++m) {
                float x = acc[i][m];
                x += __shfl_xor(x, 1, 64);
                x += __shfl_xor(x, 2, 64);
                x += __shfl_xor(x, 4, 64);
                x += __shfl_xor(x, 8, 64);
                acc[i][m] = x;
            }
        if (ds == 0) {
#pragma unroll
            for (int i = 0; i < 4; ++i)
#pragma unroll
                for (int m = 0; m < Mn; ++m)
                    redS[(4 * bg + i) * Mn + m] = acc[i][m];
        }
    } else {
        // ---- gram wave: lane (q = l>>4, s = l&15); d = 4s+64k+{0..3};
        //      group q owns a compile-time pair range
        const int l = tid - 256;
        const int q = l >> 4;
        const int s = l & 15;

        float g[17];
#pragma unroll
        for (int j = 0; j < 17; ++j) g[j] = 0.f;

#pragma unroll 2
        for (int k = 0; k < 16; ++k) {
            float4 v[Mn];
#pragma unroll
            for (int m = 0; m < Mn; ++m)
                v[m] = *reinterpret_cast<const float4*>(
                    &memL[m * Dn + 4 * s + 64 * k]);
            if (q == 0)      gramPairs<0, 17>(v, g);
            else if (q == 1) gramPairs<17, 34>(v, g);
            else if (q == 2) gramPairs<34, 50>(v, g);
            else             gramPairs<50, 66>(v, g);
        }
        // reduce over the 16 s lanes within each group
#pragma unroll
        for (int j = 0; j < 17; ++j) {
            float x = g[j];
            x += __shfl_xor(x, 1, 64);
            x += __shfl_xor(x, 2, 64);
            x += __shfl_xor(x, 4, 64);
            x += __shfl_xor(x, 8, 64);
            g[j] = x;
        }
        const int p0 = (q == 0) ? 0 : (q == 1) ? 17 : (q == 2) ? 34 : 50;
        const int np = (q < 2) ? 17 : 16;
        if (s == 0) {
#pragma unroll
            for (int j = 0; j < 17; ++j)      // j compile-time, guard runtime
                if (j < np) redG[p0 + j] = g[j];
        }
    }

    __syncthreads();

    // ---- finish: one thread per b (wave 0)
    if (tid < Bn) {
        const int b = tid;
        float w[Mn];
        float numer = 0.f;
#pragma unroll
        for (int m = 0; m < Mn; ++m) {
            const float s = redS[b * Mn + m];
            w[m]  = __expf(BETA * (s - 1.f));
            numer = fmaf(w[m], s, numer);
        }
        float den2 = 0.f;
#pragma unroll
        for (int p = 0; p < NP; ++p) {
            const float t = w[pairI(p)] * w[pairJ(p)] * redG[p];
            den2 += (pairI(p) == pairJ(p)) ? t : (2.f * t);
        }
        out[b * Cn + c] = 100.f * numer / sqrtf(den2);
    }
}

extern "C" void kernel_launch(void* const* d_in, const int* in_sizes, int n_in,
                              void* d_out, int out_size, void* d_ws, size_t ws_size,
                              hipStream_t stream) {
    const float* img = (const float*)d_in[0];  // [64][1024] f32
    const float* mem = (const float*)d_in[1];  // [1000][11][1024] f32
    float* out = (float*)d_out;                // [64][1000] f32
    (void)in_sizes; (void)n_in; (void)out_size; (void)d_ws; (void)ws_size;
    dualmem_kernel<<<dim3(Cn), dim3(320), 0, stream>>>(img, mem, out);
}

// Round 6
// 252.877 us; speedup vs baseline: 2.9915x; 2.9915x over previous
//
#include <hip/hip_runtime.h>

// DualMem fast_get_image_pred:
//   logits[b,c] = 100 * (Σ_m w_m sim_m) / sqrt(Σ_{i,j} w_i w_j G[c,i,j])
//
// Unified lesson R1/R3/R5: every kernel whose per-thread live set
// (persistent acc + batched load transients) exceeded its VGPR allocation
// spilled to scratch; scratch is L2-absorbed (invisible in HBM-only
// FETCH/WRITE counters) and the in-loop round-trips produce the
// ~450-770us all-pipes-idle signature. Keep live <= ~80, fence transient
// batching with sched_barrier(0).
// R4 lesson: loads whose address ignores most lane bits are wave-duplicated
// through L1 (16-way dup = 3.1GB L1 traffic = 105us). Make addresses
// 64-lane-distinct.
//
// Structure: 3 simple kernels (independent regalloc, no barriers, no
// cross-role stragglers).
//   K1 sim:  grid(4,1000); wave owns 4 b-rows, lane l owns d=4l+256k.
//            acc[4][11]=44, transients fenced at ~16 -> ~75 live.
//   K2 gram: unchanged from R4 (lane-distinct already).
//   K3 finish: unchanged from R4.

constexpr int Bn = 64;     // batch
constexpr int Cn = 1000;   // classes
constexpr int Mn = 11;     // memories per class
constexpr int Dn = 1024;   // feature dim
constexpr int NP = 66;     // Mn*(Mn+1)/2 unique Gram pairs
constexpr float BETA = 5.5f;

// p-th pair (i<=j) of the upper-triangular 11x11 Gram (compile-time p only!)
constexpr int pairI(int p) {
    int i = 0;
    while (p >= Mn - i) { p -= Mn - i; ++i; }
    return i;
}
constexpr int pairJ(int p) {
    int i = 0;
    while (p >= Mn - i) { p -= Mn - i; ++i; }
    return i + p;
}

// ---------------- K1: sim[c][b][m] ----------------
__global__ __launch_bounds__(256) void sim_kernel(
    const float* __restrict__ img, const float* __restrict__ mem,
    float* __restrict__ sim) {
    const int bg = blockIdx.x;         // b-group of 16 (grid.x=4, consecutive blocks share c)
    const int c  = blockIdx.y;         // class
    const int w  = threadIdx.x >> 6;   // wave 0..3
    const int l  = threadIdx.x & 63;   // lane: d = 4*l + 256*k + {0..3}
    const int b0 = bg * 16 + w * 4;    // this wave's 4 b-rows

    const float* ip = img + b0 * Dn + 4 * l;
    const float* mp = mem + (size_t)c * (Mn * Dn) + 4 * l;

    float acc[4][Mn];
#pragma unroll
    for (int i = 0; i < 4; ++i)
#pragma unroll
        for (int m = 0; m < Mn; ++m) acc[i][m] = 0.f;

#pragma unroll
    for (int k = 0; k < 4; ++k) {
        float4 iv[4];
#pragma unroll
        for (int i = 0; i < 4; ++i)
            iv[i] = *reinterpret_cast<const float4*>(ip + i * Dn + 256 * k);
        __builtin_amdgcn_sched_barrier(0);  // cap transient batch: iv only
#pragma unroll
        for (int m = 0; m < Mn; ++m) {
            const float4 mv = *reinterpret_cast<const float4*>(mp + m * Dn + 256 * k);
#pragma unroll
            for (int i = 0; i < 4; ++i) {
                float a = acc[i][m];
                a = fmaf(iv[i].x, mv.x, a);
                a = fmaf(iv[i].y, mv.y, a);
                a = fmaf(iv[i].z, mv.z, a);
                a = fmaf(iv[i].w, mv.w, a);
                acc[i][m] = a;
            }
            if (m == 3 || m == 7) __builtin_amdgcn_sched_barrier(0);  // <=4 mv in flight
        }
    }

    // full 64-lane butterfly reduce of each of the 44 partial dots
#pragma unroll
    for (int i = 0; i < 4; ++i)
#pragma unroll
        for (int m = 0; m < Mn; ++m) {
            float x = acc[i][m];
            x += __shfl_xor(x, 1, 64);
            x += __shfl_xor(x, 2, 64);
            x += __shfl_xor(x, 4, 64);
            x += __shfl_xor(x, 8, 64);
            x += __shfl_xor(x, 16, 64);
            x += __shfl_xor(x, 32, 64);
            acc[i][m] = x;
        }

    if (l == 0) {
        float* o = sim + (size_t)c * (Bn * Mn) + b0 * Mn;  // 44 contiguous floats
#pragma unroll
        for (int i = 0; i < 4; ++i)
#pragma unroll
            for (int m = 0; m < Mn; ++m) o[i * Mn + m] = acc[i][m];
    }
}

// ---------------- K2: gram[c][p] (unchanged from R4) ----------------
template <int P0, int P1>
__device__ inline void gramPairs(const float4* v, float* g) {
#pragma unroll
    for (int p = P0; p < P1; ++p) {           // p compile-time after unroll
        const float4 a = v[pairI(p)];
        const float4 b = v[pairJ(p)];
        float x = g[p - P0];
        x = fmaf(a.x, b.x, x);
        x = fmaf(a.y, b.y, x);
        x = fmaf(a.z, b.z, x);
        x = fmaf(a.w, b.w, x);
        g[p - P0] = x;
    }
}

__global__ __launch_bounds__(256) void gram_kernel(
    const float* __restrict__ mem, float* __restrict__ gram) {
    const int c = blockIdx.x;
    const int w = threadIdx.x >> 6;    // wave: pair group
    const int l = threadIdx.x & 63;    // lane: d = 4*l + 256*k + {0..3}

    const float* mp = mem + (size_t)c * (Mn * Dn) + 4 * l;

    float g[17];
#pragma unroll
    for (int q = 0; q < 17; ++q) g[q] = 0.f;

    for (int k = 0; k < 4; ++k) {
        float4 v[Mn];
#pragma unroll
        for (int m = 0; m < Mn; ++m)
            v[m] = *reinterpret_cast<const float4*>(mp + m * Dn + 256 * k);
        if (w == 0)      gramPairs<0, 17>(v, g);
        else if (w == 1) gramPairs<17, 34>(v, g);
        else if (w == 2) gramPairs<34, 50>(v, g);
        else             gramPairs<50, 66>(v, g);
    }
#pragma unroll
    for (int q = 0; q < 17; ++q) {
        float x = g[q];
        x += __shfl_xor(x, 1, 64);
        x += __shfl_xor(x, 2, 64);
        x += __shfl_xor(x, 4, 64);
        x += __shfl_xor(x, 8, 64);
        x += __shfl_xor(x, 16, 64);
        x += __shfl_xor(x, 32, 64);
        g[q] = x;
    }
    const int np = (w < 2) ? 17 : 16;
    const int p0 = (w == 0) ? 0 : (w == 1) ? 17 : (w == 2) ? 34 : 50;
    if (l == 0) {
#pragma unroll
        for (int q = 0; q < 17; ++q)          // q compile-time, guard runtime
            if (q < np) gram[c * NP + p0 + q] = g[q];
    }
}

// ---------------- K3: logits (unchanged from R4) ----------------
__global__ __launch_bounds__(256) void finish_kernel(
    const float* __restrict__ sim, const float* __restrict__ gram,
    float* __restrict__ out) {
    const int b = threadIdx.x & 63;
    const int c = blockIdx.x * 4 + (threadIdx.x >> 6);

    const float* sp = sim + (size_t)c * (Bn * Mn) + b * Mn;
    const float* gp = gram + c * NP;

    float w[Mn];
    float numer = 0.f;
#pragma unroll
    for (int m = 0; m < Mn; ++m) {
        const float s = sp[m];
        w[m]  = __expf(BETA * (s - 1.f));
        numer = fmaf(w[m], s, numer);
    }
    float den2 = 0.f;
#pragma unroll
    for (int p = 0; p < NP; ++p) {
        const float t = w[pairI(p)] * w[pairJ(p)] * gp[p];
        den2 += (pairI(p) == pairJ(p)) ? t : (2.f * t);
    }
    out[b * Cn + c] = 100.f * numer / sqrtf(den2);
}

extern "C" void kernel_launch(void* const* d_in, const int* in_sizes, int n_in,
                              void* d_out, int out_size, void* d_ws, size_t ws_size,
                              hipStream_t stream) {
    const float* img = (const float*)d_in[0];  // [64][1024] f32
    const float* mem = (const float*)d_in[1];  // [1000][11][1024] f32
    float* out = (float*)d_out;                // [64][1000] f32
    (void)in_sizes; (void)n_in; (void)out_size; (void)ws_size;

    float* ws_sim  = (float*)d_ws;             // [1000][64][11]
    float* ws_gram = ws_sim + Cn * Bn * Mn;    // [1000][66]

    sim_kernel<<<dim3(4, Cn), dim3(256), 0, stream>>>(img, mem, ws_sim);
    gram_kernel<<<dim3(Cn), dim3(256), 0, stream>>>(mem, ws_gram);
    finish_kernel<<<dim3(Cn / 4), dim3(256), 0, stream>>>(ws_sim, ws_gram, out);
}

// Round 7
// 145.732 us; speedup vs baseline: 5.1908x; 1.7352x over previous
//
#include <hip/hip_runtime.h>

// DualMem fast_get_image_pred, single fused kernel:
//   logits[b,c] = 100 * (Σ_m w_m sim_m) / sqrt(Σ_{i,j} w_i w_j G[c,i,j])
//
// Lessons driving this structure:
//  R1/R3/R5: live-set > VGPR alloc => scratch round-trips => all-pipes-idle.
//    R5's root cause refined: 320-thread block made the compiler self-cap at
//    88 VGPR (targeting 4 blocks/CU). 256-thread blocks get 128-144.
//    Fix: 256 threads + __launch_bounds__(256,2) => cap 256, need ~150.
//  R4: broadcast-duplicated global loads are L1-BW-bound (16x dup = 3.1GB).
//    Fix: mem broadcasts belong in LDS (free), img loads lane-distinct.
//  R6: sched_barrier(0) fences defeat load pipelining => latency-bound at 6%
//    BW; multi-XCD same-class blocks duplicate L2 fills (FETCH 23->88MB).
//    Fix: no fences; one block per class (grid=1000, no same-class dup).
//
// Structure: grid=1000 (one class/block), 256 threads. Stage mem[c] (45KB)
// in LDS once. All 4 waves: sim (thread owns 4 b x 11 m, d-slice ds=tid&15),
// then gram (R4-proven 17-pair compile-time groups), then fused finish.
// Two barriers, zero workspace, one dispatch.

constexpr int Bn = 64;     // batch
constexpr int Cn = 1000;   // classes
constexpr int Mn = 11;     // memories per class
constexpr int Dn = 1024;   // feature dim
constexpr int NP = 66;     // Mn*(Mn+1)/2 unique Gram pairs
constexpr float BETA = 5.5f;

// p-th pair (i<=j) of the upper-triangular 11x11 Gram (compile-time p only!)
constexpr int pairI(int p) {
    int i = 0;
    while (p >= Mn - i) { p -= Mn - i; ++i; }
    return i;
}
constexpr int pairJ(int p) {
    int i = 0;
    while (p >= Mn - i) { p -= Mn - i; ++i; }
    return i + p;
}

template <int P0, int P1>
__device__ inline void gramPairs(const float4* v, float* g) {
#pragma unroll
    for (int p = P0; p < P1; ++p) {           // p compile-time after unroll
        const float4 a = v[pairI(p)];
        const float4 b = v[pairJ(p)];
        float x = g[p - P0];
        x = fmaf(a.x, b.x, x);
        x = fmaf(a.y, b.y, x);
        x = fmaf(a.z, b.z, x);
        x = fmaf(a.w, b.w, x);
        g[p - P0] = x;
    }
}

__global__ __launch_bounds__(256, 2) void dualmem_kernel(
    const float* __restrict__ img, const float* __restrict__ mem,
    float* __restrict__ out) {
    __shared__ float memL[Mn * Dn];   // staged mem[c], linear (45 KB)
    __shared__ float redS[Bn * Mn];   // reduced sims [b][m]
    __shared__ float redG[NP];        // reduced Gram pairs

    const int c   = blockIdx.x;
    const int tid = threadIdx.x;
    const float* __restrict__ memc = mem + (size_t)c * (Mn * Dn);

    // ---- stage mem[c] into LDS: coalesced float4
    for (int u = tid; u < Mn * Dn / 4; u += 256) {
        const float4 v = *reinterpret_cast<const float4*>(memc + 4 * u);
        *reinterpret_cast<float4*>(&memL[4 * u]) = v;
    }
    __syncthreads();

    // ---- sim phase: thread (bg, ds) owns b = 4bg..4bg+3, d = 4ds+64k+{0..3}
    {
        const int ds = tid & 15;
        const int bg = tid >> 4;
        const float* ip = img + (4 * bg) * Dn + 4 * ds;

        float acc[4][Mn];
#pragma unroll
        for (int i = 0; i < 4; ++i)
#pragma unroll
            for (int m = 0; m < Mn; ++m) acc[i][m] = 0.f;

        for (int k = 0; k < 16; ++k) {   // NOT unrolled — let compiler pipeline
            float4 iv[4];
#pragma unroll
            for (int i = 0; i < 4; ++i)
                iv[i] = *reinterpret_cast<const float4*>(ip + i * Dn + 64 * k);
#pragma unroll
            for (int m = 0; m < Mn; ++m) {
                const float4 mv = *reinterpret_cast<const float4*>(
                    &memL[m * Dn + 4 * ds + 64 * k]);
#pragma unroll
                for (int i = 0; i < 4; ++i) {
                    float a = acc[i][m];
                    a = fmaf(iv[i].x, mv.x, a);
                    a = fmaf(iv[i].y, mv.y, a);
                    a = fmaf(iv[i].z, mv.z, a);
                    a = fmaf(iv[i].w, mv.w, a);
                    acc[i][m] = a;
                }
            }
        }
        // reduce over the 16 ds lanes (low 4 lane bits)
#pragma unroll
        for (int i = 0; i < 4; ++i)
#pragma unroll
            for (int m = 0; m < Mn; ++m) {
                float x = acc[i][m];
                x += __shfl_xor(x, 1, 64);
                x += __shfl_xor(x, 2, 64);
                x += __shfl_xor(x, 4, 64);
                x += __shfl_xor(x, 8, 64);
                acc[i][m] = x;
            }
        if (ds == 0) {
#pragma unroll
            for (int i = 0; i < 4; ++i)
#pragma unroll
                for (int m = 0; m < Mn; ++m)
                    redS[(4 * bg + i) * Mn + m] = acc[i][m];
        }
    }

    // ---- gram phase (same LDS data; acc registers are dead now)
    {
        const int w = tid >> 6;    // wave: pair group
        const int l = tid & 63;    // lane: d = 4*l + 256*k + {0..3}

        float g[17];
#pragma unroll
        for (int q = 0; q < 17; ++q) g[q] = 0.f;

        for (int k = 0; k < 4; ++k) {
            float4 v[Mn];
#pragma unroll
            for (int m = 0; m < Mn; ++m)
                v[m] = *reinterpret_cast<const float4*>(
                    &memL[m * Dn + 4 * l + 256 * k]);
            if (w == 0)      gramPairs<0, 17>(v, g);
            else if (w == 1) gramPairs<17, 34>(v, g);
            else if (w == 2) gramPairs<34, 50>(v, g);
            else             gramPairs<50, 66>(v, g);
        }
#pragma unroll
        for (int q = 0; q < 17; ++q) {
            float x = g[q];
            x += __shfl_xor(x, 1, 64);
            x += __shfl_xor(x, 2, 64);
            x += __shfl_xor(x, 4, 64);
            x += __shfl_xor(x, 8, 64);
            x += __shfl_xor(x, 16, 64);
            x += __shfl_xor(x, 32, 64);
            g[q] = x;
        }
        const int np = (w < 2) ? 17 : 16;
        const int p0 = (w == 0) ? 0 : (w == 1) ? 17 : (w == 2) ? 34 : 50;
        if (l == 0) {
#pragma unroll
            for (int q = 0; q < 17; ++q)      // q compile-time, guard runtime
                if (q < np) redG[p0 + q] = g[q];
        }
    }

    __syncthreads();

    // ---- finish: one thread per b (wave 0)
    if (tid < Bn) {
        const int b = tid;
        float w[Mn];
        float numer = 0.f;
#pragma unroll
        for (int m = 0; m < Mn; ++m) {
            const float s = redS[b * Mn + m];
            w[m]  = __expf(BETA * (s - 1.f));
            numer = fmaf(w[m], s, numer);
        }
        float den2 = 0.f;
#pragma unroll
        for (int p = 0; p < NP; ++p) {
            const float t = w[pairI(p)] * w[pairJ(p)] * redG[p];
            den2 += (pairI(p) == pairJ(p)) ? t : (2.f * t);
        }
        out[b * Cn + c] = 100.f * numer / sqrtf(den2);
    }
}

extern "C" void kernel_launch(void* const* d_in, const int* in_sizes, int n_in,
                              void* d_out, int out_size, void* d_ws, size_t ws_size,
                              hipStream_t stream) {
    const float* img = (const float*)d_in[0];  // [64][1024] f32
    const float* mem = (const float*)d_in[1];  // [1000][11][1024] f32
    float* out = (float*)d_out;                // [64][1000] f32
    (void)in_sizes; (void)n_in; (void)out_size; (void)d_ws; (void)ws_size;
    dualmem_kernel<<<dim3(Cn), dim3(256), 0, stream>>>(img, mem, out);
}

// Round 8
// 144.420 us; speedup vs baseline: 5.2380x; 1.0091x over previous
//
#include <hip/hip_runtime.h>

// DualMem fast_get_image_pred, single fused kernel:
//   logits[b,c] = 100 * (Σ_m w_m sim_m) / sqrt(Σ_{i,j} w_i w_j G[c,i,j])
//
// Lessons:
//  R1/R5/R7: __launch_bounds__ second arg (or 320-thread blocks) makes the
//    allocator self-cap (64/88/88 VGPR) and spill; plain (256) gives 128-144.
//    NEVER pass the second arg here.
//  R7: even at 88 VGPR the structure must not need more — sim live-set cut
//    from ~90 to ~55 by splitting m across lanes: thread owns 4b x 6m x 8ds.
//    Mn=11 padded to 12 LDS rows (row 11 zeroed) so the m-split never
//    diverges; padded sims land in a redS column that finish never reads.
//  R4: broadcast loads belong in LDS; img loads stay lane-distinct global.
//  R6: no sched_barrier fences; one block per class (no cross-XCD dup).

constexpr int Bn = 64;     // batch
constexpr int Cn = 1000;   // classes
constexpr int Mn = 11;     // memories per class
constexpr int MPAD = 12;   // padded m (row 11 zeroed)
constexpr int Dn = 1024;   // feature dim
constexpr int NP = 66;     // Mn*(Mn+1)/2 unique Gram pairs
constexpr float BETA = 5.5f;

// p-th pair (i<=j) of the upper-triangular 11x11 Gram (compile-time p only!)
constexpr int pairI(int p) {
    int i = 0;
    while (p >= Mn - i) { p -= Mn - i; ++i; }
    return i;
}
constexpr int pairJ(int p) {
    int i = 0;
    while (p >= Mn - i) { p -= Mn - i; ++i; }
    return i + p;
}

template <int P0, int P1>
__device__ inline void gramPairs(const float4* v, float* g) {
#pragma unroll
    for (int p = P0; p < P1; ++p) {           // p compile-time after unroll
        const float4 a = v[pairI(p)];
        const float4 b = v[pairJ(p)];
        float x = g[p - P0];
        x = fmaf(a.x, b.x, x);
        x = fmaf(a.y, b.y, x);
        x = fmaf(a.z, b.z, x);
        x = fmaf(a.w, b.w, x);
        g[p - P0] = x;
    }
}

__global__ __launch_bounds__(256) void dualmem_kernel(
    const float* __restrict__ img, const float* __restrict__ mem,
    float* __restrict__ out) {
    __shared__ float memL[MPAD * Dn];   // staged mem[c] + zero row (48 KB)
    __shared__ float redS[Bn * MPAD];   // reduced sims [b][m] (padded)
    __shared__ float redG[NP];          // reduced Gram pairs

    const int c   = blockIdx.x;
    const int tid = threadIdx.x;
    const float* __restrict__ memc = mem + (size_t)c * (Mn * Dn);

    // ---- stage mem[c] into LDS (coalesced float4); zero the pad row
    for (int u = tid; u < Mn * Dn / 4; u += 256) {
        const float4 v = *reinterpret_cast<const float4*>(memc + 4 * u);
        *reinterpret_cast<float4*>(&memL[4 * u]) = v;
    }
    for (int u = tid; u < Dn; u += 256) memL[Mn * Dn + u] = 0.f;
    __syncthreads();

    // ---- sim phase: thread (bg, mh, ds) owns b=4bg..4bg+3, m=6mh..6mh+5,
    //      d = 4*ds + 32*k + {0..3}
    {
        const int ds = tid & 7;          // lane bits 0-2
        const int mh = (tid >> 3) & 1;   // lane bit 3 (m-half)
        const int bg = tid >> 4;
        const int m0 = mh * 6;
        const float* ip = img + (4 * bg) * Dn + 4 * ds;

        float acc[4][6];
#pragma unroll
        for (int i = 0; i < 4; ++i)
#pragma unroll
            for (int j = 0; j < 6; ++j) acc[i][j] = 0.f;

        for (int k = 0; k < 32; ++k) {   // not unrolled — compiler pipelines
            float4 iv[4];
#pragma unroll
            for (int i = 0; i < 4; ++i)
                iv[i] = *reinterpret_cast<const float4*>(ip + i * Dn + 32 * k);
#pragma unroll
            for (int j = 0; j < 6; ++j) {
                const float4 mv = *reinterpret_cast<const float4*>(
                    &memL[(m0 + j) * Dn + 4 * ds + 32 * k]);
#pragma unroll
                for (int i = 0; i < 4; ++i) {
                    float a = acc[i][j];
                    a = fmaf(iv[i].x, mv.x, a);
                    a = fmaf(iv[i].y, mv.y, a);
                    a = fmaf(iv[i].z, mv.z, a);
                    a = fmaf(iv[i].w, mv.w, a);
                    acc[i][j] = a;
                }
            }
        }
        // reduce over the 8 ds lanes (lane bits 0-2 only; mh/bg untouched)
#pragma unroll
        for (int i = 0; i < 4; ++i)
#pragma unroll
            for (int j = 0; j < 6; ++j) {
                float x = acc[i][j];
                x += __shfl_xor(x, 1, 64);
                x += __shfl_xor(x, 2, 64);
                x += __shfl_xor(x, 4, 64);
                acc[i][j] = x;
            }
        if (ds == 0) {
#pragma unroll
            for (int i = 0; i < 4; ++i)
#pragma unroll
                for (int j = 0; j < 6; ++j)
                    redS[(4 * bg + i) * MPAD + m0 + j] = acc[i][j];
        }
    }

    // ---- gram phase (same LDS data; sim registers dead now)
    {
        const int w = tid >> 6;    // wave: pair group
        const int l = tid & 63;    // lane: d = 4*l + 256*k + {0..3}

        float g[17];
#pragma unroll
        for (int q = 0; q < 17; ++q) g[q] = 0.f;

        for (int k = 0; k < 4; ++k) {
            float4 v[Mn];
#pragma unroll
            for (int m = 0; m < Mn; ++m)
                v[m] = *reinterpret_cast<const float4*>(
                    &memL[m * Dn + 4 * l + 256 * k]);
            if (w == 0)      gramPairs<0, 17>(v, g);
            else if (w == 1) gramPairs<17, 34>(v, g);
            else if (w == 2) gramPairs<34, 50>(v, g);
            else             gramPairs<50, 66>(v, g);
        }
#pragma unroll
        for (int q = 0; q < 17; ++q) {
            float x = g[q];
            x += __shfl_xor(x, 1, 64);
            x += __shfl_xor(x, 2, 64);
            x += __shfl_xor(x, 4, 64);
            x += __shfl_xor(x, 8, 64);
            x += __shfl_xor(x, 16, 64);
            x += __shfl_xor(x, 32, 64);
            g[q] = x;
        }
        const int np = (w < 2) ? 17 : 16;
        const int p0 = (w == 0) ? 0 : (w == 1) ? 17 : (w == 2) ? 34 : 50;
        if (l == 0) {
#pragma unroll
            for (int q = 0; q < 17; ++q)      // q compile-time, guard runtime
                if (q < np) redG[p0 + q] = g[q];
        }
    }

    __syncthreads();

    // ---- finish: one thread per b (wave 0)
    if (tid < Bn) {
        const int b = tid;
        float w[Mn];
        float numer = 0.f;
#pragma unroll
        for (int m = 0; m < Mn; ++m) {
            const float s = redS[b * MPAD + m];
            w[m]  = __expf(BETA * (s - 1.f));
            numer = fmaf(w[m], s, numer);
        }
        float den2 = 0.f;
#pragma unroll
        for (int p = 0; p < NP; ++p) {
            const float t = w[pairI(p)] * w[pairJ(p)] * redG[p];
            den2 += (pairI(p) == pairJ(p)) ? t : (2.f * t);
        }
        out[b * Cn + c] = 100.f * numer / sqrtf(den2);
    }
}

extern "C" void kernel_launch(void* const* d_in, const int* in_sizes, int n_in,
                              void* d_out, int out_size, void* d_ws, size_t ws_size,
                              hipStream_t stream) {
    const float* img = (const float*)d_in[0];  // [64][1024] f32
    const float* mem = (const float*)d_in[1];  // [1000][11][1024] f32
    float* out = (float*)d_out;                // [64][1000] f32
    (void)in_sizes; (void)n_in; (void)out_size; (void)d_ws; (void)ws_size;
    dualmem_kernel<<<dim3(Cn), dim3(256), 0, stream>>>(img, mem, out);
}